// Round 4
// baseline (5366.598 us; speedup 1.0000x reference)
//
#include <hip/hip_runtime.h>
#include <hip/hip_bf16.h>
#include <math.h>

// Problem constants
#define NN   16
#define CI   64
#define HH   224
#define WW   224
#define CO   128
#define OHH  222
#define OWW  222
#define HW   (HH*WW)   // 50176

// ws holds only prep_w's B fragments (144 KB).
#define WS_NEED (36*4*64*16)   // 147456

typedef short  short8  __attribute__((ext_vector_type(8)));
typedef float  f32x16  __attribute__((ext_vector_type(16)));
typedef float  f32x4   __attribute__((ext_vector_type(4)));

__device__ static inline unsigned f2bf_pk(float a, float b) {
  __hip_bfloat162 h = __float22bfloat162_rn(make_float2(a, b));  // v_cvt_pk_bf16_f32
  return *reinterpret_cast<unsigned*>(&h);
}

// ---------------------------------------------------------------------------
// prep_w: weights [Co][Ci][3][3] fp32 -> B fragments in CONSUMPTION order.
// Global step g = h*18 + tap*2 + cicl (h = ci-half, tap = kh*3+kw, cicl 0/1).
// ci-chunk cic = h*2 + cicl (16 ci each). Fragment f = g*4 + ctg, ctg = co/32.
// Within frag: n = lane&31 (co in 32-tile), k = (lane>>5)*8 + j.
// ---------------------------------------------------------------------------
__global__ __launch_bounds__(256) void prep_w_kernel(const float* __restrict__ wt,
                                                     unsigned char* __restrict__ ws) {
  int t    = blockIdx.x * 256 + threadIdx.x;       // 0..9215
  int lane = t & 63;
  int f    = t >> 6;                               // 0..143
  int g    = f >> 2;                               // 0..35
  int ctg  = f & 3;
  int h    = g / 18;
  int rem  = g % 18;
  int tap  = rem >> 1;
  int cicl = rem & 1;
  int kh   = tap / 3, kw = tap % 3;
  int cic  = h * 2 + cicl;
  int co   = ctg * 32 + (lane & 31);
  int k0   = cic * 16 + (lane >> 5) * 8;
  unsigned pk[4];
#pragma unroll
  for (int j = 0; j < 4; ++j) {
    int ci0 = k0 + 2 * j;
    float a = wt[(size_t)co * 576 + (ci0    ) * 9 + kh * 3 + kw];
    float b = wt[(size_t)co * 576 + (ci0 + 1) * 9 + kh * 3 + kw];
    pk[j] = f2bf_pk(a, b);
  }
  ((uint4*)ws)[t] = make_uint4(pk[0], pk[1], pk[2], pk[3]);
}

// ---------------------------------------------------------------------------
// conv v4: ci-split implicit GEMM, LDS 25.3 KB -> 6 blocks/CU (24 waves).
// Block 256 thr / 4 waves: tile 4 oh x 64 ow x 128 co. Wave (mg, ng):
// mtl = 4 m-tiles (2 ohl x 2 owh), ct = 2 co-tiles; acc 128 (AGPR).
// Phase h stages 32 ci (6 rows x 66 cols, 64-B rotated slots); phase-1 x
// loads issued before phase-0 K-loop (HBM latency hidden by 18 MFMA steps).
// ---------------------------------------------------------------------------
__global__ __launch_bounds__(256, 6) void conv_min_kernel(
    const float* __restrict__ x, const float* __restrict__ bias,
    const unsigned char* __restrict__ ws, float* __restrict__ out) {
  __shared__ __align__(16) unsigned char smem[6 * 66 * 64];  // 25344 B

  int bid  = blockIdx.x;
  int owt  = bid & 3;
  int rest = bid >> 2;
  int oht  = rest % 56;
  int n    = rest / 56;
  int ow0  = (owt < 3) ? owt * 64 : 158;   // last ow tile overlaps (same values)
  int oh0  = oht * 4;                      // oh 222/223 masked at store

  int tid   = threadIdx.x;
  int wv    = tid >> 6;
  int lane  = tid & 63;
  int mg    = wv >> 1;     // oh row-pair
  int ng    = wv & 1;      // co half
  int mrow  = lane & 31;
  int khalf = lane >> 5;

  // ---- B prologue: first two steps' fragments (L2-resident stream) ----
  const short8* wf = (const short8*)ws;
  short8 bb[3][2];
#pragma unroll
  for (int ct = 0; ct < 2; ++ct) {
    bb[0][ct] = wf[(size_t)((0 * 4) + ng * 2 + ct) * 64 + lane];
    bb[1][ct] = wf[(size_t)((1 * 4) + ng * 2 + ct) * 64 + lane];
  }

  // ---- staging thread mapping: col = tid&63, ci-chunk cc = tid>>6 ----
  int scol = tid & 63;
  int scc  = tid >> 6;
  int srot = ((scc + scol) & 3) << 4;
  const float* xc = x + (size_t)n * CI * HW + ow0 + scol;
  bool ex = tid < 48;                       // extra cols 64,65
  int er = tid >> 3, esub = tid & 7;
  int ecol = 64 + (esub & 1), ecc = esub >> 1;
  int erot = ((ecc + ecol) & 3) << 4;

  // ---- phase-0 x loads (ci 0..31) + pack ----
  unsigned p0[6][4], pe0[4];
#pragma unroll
  for (int r = 0; r < 6; ++r) {
    int rg = oh0 + r; if (rg > 223) rg = 223;
    const float* xr = xc + rg * 224 + (size_t)(scc * 8) * HW;
    float v[8];
#pragma unroll
    for (int j = 0; j < 8; ++j) v[j] = xr[(size_t)j * HW];
#pragma unroll
    for (int k = 0; k < 4; ++k) p0[r][k] = f2bf_pk(v[2 * k], v[2 * k + 1]);
  }
  if (ex) {
    int rg = oh0 + er; if (rg > 223) rg = 223;
    const float* xr = x + (size_t)n * CI * HW + (size_t)(ecc * 8) * HW + rg * 224 + ow0 + ecol;
    float v[8];
#pragma unroll
    for (int j = 0; j < 8; ++j) v[j] = xr[(size_t)j * HW];
#pragma unroll
    for (int k = 0; k < 4; ++k) pe0[k] = f2bf_pk(v[2 * k], v[2 * k + 1]);
  }
  // ---- write phase-0 tile ----
#pragma unroll
  for (int r = 0; r < 6; ++r)
    *(uint4*)(smem + (r * 66 + scol) * 64 + srot) = *(uint4*)p0[r];
  if (ex)
    *(uint4*)(smem + (er * 66 + ecol) * 64 + erot) = *(uint4*)pe0;

  // ---- phase-1 x loads (ci 32..63): issue NOW, consumed after K-phase-0 ----
  unsigned p1[6][4], pe1[4];
#pragma unroll
  for (int r = 0; r < 6; ++r) {
    int rg = oh0 + r; if (rg > 223) rg = 223;
    const float* xr = xc + rg * 224 + (size_t)(32 + scc * 8) * HW;
    float v[8];
#pragma unroll
    for (int j = 0; j < 8; ++j) v[j] = xr[(size_t)j * HW];
#pragma unroll
    for (int k = 0; k < 4; ++k) p1[r][k] = f2bf_pk(v[2 * k], v[2 * k + 1]);
  }
  if (ex) {
    int rg = oh0 + er; if (rg > 223) rg = 223;
    const float* xr = x + (size_t)n * CI * HW + (size_t)(32 + ecc * 8) * HW + rg * 224 + ow0 + ecol;
    float v[8];
#pragma unroll
    for (int j = 0; j < 8; ++j) v[j] = xr[(size_t)j * HW];
#pragma unroll
    for (int k = 0; k < 4; ++k) pe1[k] = f2bf_pk(v[2 * k], v[2 * k + 1]);
  }

  // ---- acc init with bias ----
  f32x16 acc[4][2];
#pragma unroll
  for (int ct = 0; ct < 2; ++ct) {
    float bv = bias[ng * 64 + ct * 32 + mrow];
#pragma unroll
    for (int mtl = 0; mtl < 4; ++mtl)
#pragma unroll
      for (int r = 0; r < 16; ++r) acc[mtl][ct][r] = bv;
  }

  // ---- LDS read pointers: rot = (cicl*2 + khalf + mrow + kw) & 3 ----
  int u0 = (mrow + khalf) & 3;
  const unsigned char* Pb = smem + mg * (2 * 66 * 64) + mrow * 64;
  const unsigned char* P[4];
#pragma unroll
  for (int j = 0; j < 4; ++j) P[j] = Pb + ((u0 + j) & 3) * 16;

  short8 aa[2][4];

  // ---- one K phase: 18 steps (tap 0..8 x cicl 0..1), barrier-free ----
  auto kphase = [&](int g0) {
    // preload k=0: tap 0 (kh=kw=0), cicl 0 -> jj = 0
#pragma unroll
    for (int mtl = 0; mtl < 4; ++mtl) {
      const int ohl = mtl >> 1, owh = mtl & 1;
      aa[0][mtl] = *(const short8*)(P[0] + ((ohl * 66 + owh * 32) << 6));
    }
#pragma unroll
    for (int k = 0; k < 18; ++k) {
      const int g = g0 + k;
      if (g + 2 < 36) {
#pragma unroll
        for (int ct = 0; ct < 2; ++ct)
          bb[(g + 2) % 3][ct] = wf[(size_t)((g + 2) * 4 + ng * 2 + ct) * 64 + lane];
      }
      if (k < 17) {
        const int k1 = k + 1;
        const int tap1 = k1 >> 1, cicl1 = k1 & 1;
        const int kh1 = tap1 / 3, kw1 = tap1 % 3;
        const int jj = (2 * cicl1 + kw1) & 3;
#pragma unroll
        for (int mtl = 0; mtl < 4; ++mtl) {
          const int ohl = mtl >> 1, owh = mtl & 1;
          aa[k1 & 1][mtl] = *(const short8*)(
              P[jj] + ((((ohl + kh1) * 66) + owh * 32 + kw1) << 6));
        }
      }
#pragma unroll
      for (int mtl = 0; mtl < 4; ++mtl)
#pragma unroll
        for (int ct = 0; ct < 2; ++ct)
          acc[mtl][ct] = __builtin_amdgcn_mfma_f32_32x32x16_bf16(
              aa[k & 1][mtl], bb[g % 3][ct], acc[mtl][ct], 0, 0, 0);
    }
  };

  __syncthreads();        // phase-0 tile visible
  kphase(0);

  __syncthreads();        // all waves done reading phase-0 A (WAR)
#pragma unroll
  for (int r = 0; r < 6; ++r)
    *(uint4*)(smem + (r * 66 + scol) * 64 + srot) = *(uint4*)p1[r];
  if (ex)
    *(uint4*)(smem + (er * 66 + ecol) * 64 + erot) = *(uint4*)pe1;
  __syncthreads();        // phase-1 tile visible
  kphase(18);

  // ---- epilogue: min over 128 co ----
  // C/D: col = lane&31 (co), row = (r&3)+8*(r>>2)+4*khalf (pixel m).
  __syncthreads();        // A-tile dead; overlay reduction buffer
  float* epi = (float*)smem;   // [px 256][8 partials] = 8 KB
#pragma unroll
  for (int mtl = 0; mtl < 4; ++mtl) {
    const int ohl = mtl >> 1, owh = mtl & 1;
#pragma unroll
    for (int r = 0; r < 16; ++r) {
      float v = fminf(acc[mtl][0][r], acc[mtl][1][r]);   // min over ct
      v = fminf(v, __shfl_xor(v, 16, 64));
      v = fminf(v, __shfl_xor(v, 8, 64));
      v = fminf(v, __shfl_xor(v, 4, 64));                // min over 16 co
      if ((lane & 28) == 0) {                            // lanes 0-3, 32-35
        int px = (mg * 2 + ohl) * 64 + owh * 32 +
                 ((r & 3) + 8 * (r >> 2) + 4 * khalf);
        epi[px * 8 + ng * 4 + (lane & 3)] = v;
      }
    }
  }
  __syncthreads();
  {
    int px = tid;
    const f32x4* rp = (const f32x4*)(epi + px * 8);
    f32x4 a4 = rp[0], b4 = rp[1];
    float v = fminf(fminf(fminf(a4[0], a4[1]), fminf(a4[2], a4[3])),
                    fminf(fminf(b4[0], b4[1]), fminf(b4[2], b4[3])));
    v = tanhf(tanhf(v));
    int oh = oh0 + (px >> 6);
    if (oh < OHH)
      out[(size_t)n * (OHH * OWW) + (size_t)oh * OWW + ow0 + (px & 63)] = v;
  }
}

// ---------------------------------------------------------------------------
// Fallback (only if ws too small): direct fp32 conv, 8 px per block.
// ---------------------------------------------------------------------------
__global__ __launch_bounds__(128) void fallback_kernel(
    const float* __restrict__ x, const float* __restrict__ wt,
    const float* __restrict__ bias, float* __restrict__ out) {
  __shared__ float patch[64 * 30];
  __shared__ float red[128];
  int pb   = blockIdx.x;
  int owt  = pb % 28;
  int rest = pb / 28;
  int oh   = rest % OHH;
  int n    = rest / OHH;
  int ow0  = owt * 8;
  int tid  = threadIdx.x;
  for (int i = tid; i < 1920; i += 128) {
    int wl = i % 10;
    int rr = (i / 10) % 3;
    int ci = i / 30;
    int wg = ow0 + wl;
    float v = 0.f;
    if (wg < WW) v = x[((size_t)(n * 64 + ci) * HH + (oh + rr)) * WW + wg];
    patch[i] = v;
  }
  __syncthreads();
  int co = tid;
  float a[8];
#pragma unroll
  for (int p = 0; p < 8; ++p) a[p] = bias[co];
  for (int ci = 0; ci < 64; ++ci) {
#pragma unroll
    for (int rr = 0; rr < 3; ++rr)
#pragma unroll
      for (int kw = 0; kw < 3; ++kw) {
        float wvv = wt[(size_t)co * 576 + ci * 9 + rr * 3 + kw];
        const float* pp = &patch[ci * 30 + rr * 10 + kw];
#pragma unroll
        for (int p = 0; p < 8; ++p) a[p] += pp[p] * wvv;
      }
  }
  for (int p = 0; p < 8; ++p) {
    red[tid] = a[p];
    __syncthreads();
    for (int st = 64; st > 0; st >>= 1) {
      if (tid < st) red[tid] = fminf(red[tid], red[tid + st]);
      __syncthreads();
    }
    if (tid == 0 && (ow0 + p) < OWW)
      out[(size_t)n * (OHH * OWW) + (size_t)oh * OWW + ow0 + p] = tanhf(tanhf(red[0]));
    __syncthreads();
  }
}

// ---------------------------------------------------------------------------
extern "C" void kernel_launch(void* const* d_in, const int* in_sizes, int n_in,
                              void* d_out, int out_size, void* d_ws, size_t ws_size,
                              hipStream_t stream) {
  const float* x    = (const float*)d_in[0];
  const float* wt   = (const float*)d_in[1];
  const float* bias = (const float*)d_in[2];
  float* out        = (float*)d_out;

  if (ws_size >= WS_NEED) {
    unsigned char* ws = (unsigned char*)d_ws;
    prep_w_kernel<<<36, 256, 0, stream>>>(wt, ws);
    conv_min_kernel<<<NN * 56 * 4, 256, 0, stream>>>(x, bias, ws, out);
  } else {
    fallback_kernel<<<NN * OHH * 28, 128, 0, stream>>>(x, wt, bias, out);
  }
}

// Round 5
// 3477.506 us; speedup vs baseline: 1.5432x; 1.5432x over previous
//
#include <hip/hip_runtime.h>
#include <hip/hip_bf16.h>
#include <math.h>

// Problem constants
#define NN   16
#define CI   64
#define HH   224
#define WW   224
#define CO   128
#define OHH  222
#define OWW  222
#define HW   (HH*WW)   // 50176

// ws holds only prep_w's B fragments (144 KB).
#define WS_NEED (36*4*64*16)   // 147456

// LDS A-tile: 6 rows x 66 cols, 64 B payload per (row,col) slot, stride 80 B.
// 80 B = 20 words; gcd(20,32)=4 -> 8 consecutive cols cover all 32 banks:
// staging writes AND fragment reads are conflict-free (8-phase minimum).
#define CSTR 80
#define RSTR (66 * CSTR)       // 5280 B per row
#define ATILE_BYTES (6 * RSTR) // 31680 B

typedef short  short8  __attribute__((ext_vector_type(8)));
typedef float  f32x16  __attribute__((ext_vector_type(16)));
typedef float  f32x4   __attribute__((ext_vector_type(4)));

__device__ static inline unsigned f2bf_pk(float a, float b) {
  __hip_bfloat162 h = __float22bfloat162_rn(make_float2(a, b));  // v_cvt_pk_bf16_f32
  return *reinterpret_cast<unsigned*>(&h);
}

// ---------------------------------------------------------------------------
// prep_w: weights [Co][Ci][3][3] fp32 -> B fragments in CONSUMPTION order.
// Global step g = h*18 + tap*2 + cicl (h = ci-half, tap = kh*3+kw, cicl 0/1).
// ci-chunk cic = h*2 + cicl (16 ci each). Fragment f = g*4 + ctg, ctg = co/32.
// Within frag: n = lane&31 (co in 32-tile), k = (lane>>5)*8 + j.
// ---------------------------------------------------------------------------
__global__ __launch_bounds__(256) void prep_w_kernel(const float* __restrict__ wt,
                                                     unsigned char* __restrict__ ws) {
  int t    = blockIdx.x * 256 + threadIdx.x;       // 0..9215
  int lane = t & 63;
  int f    = t >> 6;                               // 0..143
  int g    = f >> 2;                               // 0..35
  int ctg  = f & 3;
  int h    = g / 18;
  int rem  = g % 18;
  int tap  = rem >> 1;
  int cicl = rem & 1;
  int kh   = tap / 3, kw = tap % 3;
  int cic  = h * 2 + cicl;
  int co   = ctg * 32 + (lane & 31);
  int k0   = cic * 16 + (lane >> 5) * 8;
  unsigned pk[4];
#pragma unroll
  for (int j = 0; j < 4; ++j) {
    int ci0 = k0 + 2 * j;
    float a = wt[(size_t)co * 576 + (ci0    ) * 9 + kh * 3 + kw];
    float b = wt[(size_t)co * 576 + (ci0 + 1) * 9 + kh * 3 + kw];
    pk[j] = f2bf_pk(a, b);
  }
  ((uint4*)ws)[t] = make_uint4(pk[0], pk[1], pk[2], pk[3]);
}

// ---------------------------------------------------------------------------
// conv v5: ci-split implicit GEMM. Block 256 thr / 4 waves: 4 oh x 64 ow x
// 128 co. Wave (mg, ng): 4 m-tiles (2 ohl x 2 owh) x 2 co-tiles; acc = 128.
// Phase h stages ci h*32..h*32+31 into the padded LDS tile; phase-1 x loads
// are issued before phase-0's 18 MFMA steps (latency hidden in-wave).
// launch_bounds(256,4): 512-reg unified budget (R4's (256,6)=341 spilled
// everything; VGPR_Count 40 + 14 GB scratch writes -- never cap that tight).
// ---------------------------------------------------------------------------
__global__ __launch_bounds__(256, 4) void conv_min_kernel(
    const float* __restrict__ x, const float* __restrict__ bias,
    const unsigned char* __restrict__ ws, float* __restrict__ out) {
  __shared__ __align__(16) unsigned char smem[ATILE_BYTES];  // 31680 B

  int bid  = blockIdx.x;
  int owt  = bid & 3;
  int rest = bid >> 2;
  int oht  = rest % 56;
  int n    = rest / 56;
  int ow0  = (owt < 3) ? owt * 64 : 158;   // last ow tile overlaps (same values)
  int oh0  = oht * 4;                      // oh 222/223 masked at store

  int tid   = threadIdx.x;
  int wv    = tid >> 6;
  int lane  = tid & 63;
  int mg    = wv >> 1;     // oh row-pair
  int ng    = wv & 1;      // co half
  int mrow  = lane & 31;
  int khalf = lane >> 5;

  // ---- B prologue: first two steps' fragments (L2-resident stream) ----
  const short8* wf = (const short8*)ws;
  short8 bb[3][2];
#pragma unroll
  for (int ct = 0; ct < 2; ++ct) {
    bb[0][ct] = wf[(size_t)((0 * 4) + ng * 2 + ct) * 64 + lane];
    bb[1][ct] = wf[(size_t)((1 * 4) + ng * 2 + ct) * 64 + lane];
  }

  // ---- staging thread mapping: col = tid&63, ci-chunk cc = tid>>6 ----
  int scol = tid & 63;
  int scc  = tid >> 6;
  const float* xc = x + (size_t)n * CI * HW + ow0 + scol;
  bool ex = tid < 48;                       // extra cols 64,65
  int er = tid >> 3, esub = tid & 7;
  int ecol = 64 + (esub & 1), ecc = esub >> 1;

  // ---- phase-0 x loads (ci 0..31) + pack ----
  unsigned p0[6][4], pe0[4];
#pragma unroll
  for (int r = 0; r < 6; ++r) {
    int rg = oh0 + r; if (rg > 223) rg = 223;
    const float* xr = xc + rg * 224 + (size_t)(scc * 8) * HW;
    float v[8];
#pragma unroll
    for (int j = 0; j < 8; ++j) v[j] = xr[(size_t)j * HW];
#pragma unroll
    for (int k = 0; k < 4; ++k) p0[r][k] = f2bf_pk(v[2 * k], v[2 * k + 1]);
  }
  if (ex) {
    int rg = oh0 + er; if (rg > 223) rg = 223;
    const float* xr = x + (size_t)n * CI * HW + (size_t)(ecc * 8) * HW + rg * 224 + ow0 + ecol;
    float v[8];
#pragma unroll
    for (int j = 0; j < 8; ++j) v[j] = xr[(size_t)j * HW];
#pragma unroll
    for (int k = 0; k < 4; ++k) pe0[k] = f2bf_pk(v[2 * k], v[2 * k + 1]);
  }
  // ---- write phase-0 tile ----
#pragma unroll
  for (int r = 0; r < 6; ++r)
    *(uint4*)(smem + r * RSTR + scol * CSTR + scc * 16) = *(uint4*)p0[r];
  if (ex)
    *(uint4*)(smem + er * RSTR + ecol * CSTR + ecc * 16) = *(uint4*)pe0;

  // ---- phase-1 x loads (ci 32..63): issue NOW, consumed after K-phase-0 ----
  unsigned p1[6][4], pe1[4];
#pragma unroll
  for (int r = 0; r < 6; ++r) {
    int rg = oh0 + r; if (rg > 223) rg = 223;
    const float* xr = xc + rg * 224 + (size_t)(32 + scc * 8) * HW;
    float v[8];
#pragma unroll
    for (int j = 0; j < 8; ++j) v[j] = xr[(size_t)j * HW];
#pragma unroll
    for (int k = 0; k < 4; ++k) p1[r][k] = f2bf_pk(v[2 * k], v[2 * k + 1]);
  }
  if (ex) {
    int rg = oh0 + er; if (rg > 223) rg = 223;
    const float* xr = x + (size_t)n * CI * HW + (size_t)(32 + ecc * 8) * HW + rg * 224 + ow0 + ecol;
    float v[8];
#pragma unroll
    for (int j = 0; j < 8; ++j) v[j] = xr[(size_t)j * HW];
#pragma unroll
    for (int k = 0; k < 4; ++k) pe1[k] = f2bf_pk(v[2 * k], v[2 * k + 1]);
  }

  // ---- acc init with bias ----
  f32x16 acc[4][2];
#pragma unroll
  for (int ct = 0; ct < 2; ++ct) {
    float bv = bias[ng * 64 + ct * 32 + mrow];
#pragma unroll
    for (int mtl = 0; mtl < 4; ++mtl)
#pragma unroll
      for (int r = 0; r < 16; ++r) acc[mtl][ct][r] = bv;
  }

  // ---- single LDS read base; every step offset is a compile-time imm ----
  // read addr = base + ((ohl+kh)*66 + owh*32 + kw)*80 + cicl*32
  const unsigned char* P0 = smem + mg * (2 * RSTR) + mrow * CSTR + khalf * 16;

  short8 aa[2][4];

  // ---- one K phase: 18 steps (tap 0..8 x cicl 0..1), barrier-free ----
  auto kphase = [&](int g0) {
    // preload k=0: kh=kw=0, cicl=0
#pragma unroll
    for (int mtl = 0; mtl < 4; ++mtl) {
      const int ohl = mtl >> 1, owh = mtl & 1;
      aa[0][mtl] = *(const short8*)(P0 + (ohl * 66 + owh * 32) * CSTR);
    }
#pragma unroll
    for (int k = 0; k < 18; ++k) {
      const int g = g0 + k;
      if (g + 2 < 36) {
#pragma unroll
        for (int ct = 0; ct < 2; ++ct)
          bb[(g + 2) % 3][ct] = wf[(size_t)((g + 2) * 4 + ng * 2 + ct) * 64 + lane];
      }
      if (k < 17) {
        const int k1 = k + 1;
        const int tap1 = k1 >> 1, cicl1 = k1 & 1;
        const int kh1 = tap1 / 3, kw1 = tap1 % 3;
#pragma unroll
        for (int mtl = 0; mtl < 4; ++mtl) {
          const int ohl = mtl >> 1, owh = mtl & 1;
          aa[k1 & 1][mtl] = *(const short8*)(
              P0 + ((ohl + kh1) * 66 + owh * 32 + kw1) * CSTR + cicl1 * 32);
        }
      }
#pragma unroll
      for (int mtl = 0; mtl < 4; ++mtl)
#pragma unroll
        for (int ct = 0; ct < 2; ++ct)
          acc[mtl][ct] = __builtin_amdgcn_mfma_f32_32x32x16_bf16(
              aa[k & 1][mtl], bb[g % 3][ct], acc[mtl][ct], 0, 0, 0);
    }
  };

  __syncthreads();        // phase-0 tile visible
  kphase(0);

  __syncthreads();        // all waves done reading phase-0 A (WAR)
#pragma unroll
  for (int r = 0; r < 6; ++r)
    *(uint4*)(smem + r * RSTR + scol * CSTR + scc * 16) = *(uint4*)p1[r];
  if (ex)
    *(uint4*)(smem + er * RSTR + ecol * CSTR + ecc * 16) = *(uint4*)pe1;
  __syncthreads();        // phase-1 tile visible
  kphase(18);

  // ---- epilogue: min over 128 co ----
  // C/D: col = lane&31 (co), row = (r&3)+8*(r>>2)+4*khalf (pixel m).
  __syncthreads();        // A-tile dead; overlay reduction buffer
  float* epi = (float*)smem;   // [px 256][8 partials] = 8 KB
#pragma unroll
  for (int mtl = 0; mtl < 4; ++mtl) {
    const int ohl = mtl >> 1, owh = mtl & 1;
#pragma unroll
    for (int r = 0; r < 16; ++r) {
      float v = fminf(acc[mtl][0][r], acc[mtl][1][r]);   // min over ct
      v = fminf(v, __shfl_xor(v, 16, 64));
      v = fminf(v, __shfl_xor(v, 8, 64));
      v = fminf(v, __shfl_xor(v, 4, 64));                // min over 16 co
      if ((lane & 28) == 0) {                            // lanes 0-3, 32-35
        int px = (mg * 2 + ohl) * 64 + owh * 32 +
                 ((r & 3) + 8 * (r >> 2) + 4 * khalf);
        epi[px * 8 + ng * 4 + (lane & 3)] = v;
      }
    }
  }
  __syncthreads();
  {
    int px = tid;
    const f32x4* rp = (const f32x4*)(epi + px * 8);
    f32x4 a4 = rp[0], b4 = rp[1];
    float v = fminf(fminf(fminf(a4[0], a4[1]), fminf(a4[2], a4[3])),
                    fminf(fminf(b4[0], b4[1]), fminf(b4[2], b4[3])));
    v = tanhf(tanhf(v));
    int oh = oh0 + (px >> 6);
    if (oh < OHH)
      out[(size_t)n * (OHH * OWW) + (size_t)oh * OWW + ow0 + (px & 63)] = v;
  }
}

// ---------------------------------------------------------------------------
// Fallback (only if ws too small): direct fp32 conv, 8 px per block.
// ---------------------------------------------------------------------------
__global__ __launch_bounds__(128) void fallback_kernel(
    const float* __restrict__ x, const float* __restrict__ wt,
    const float* __restrict__ bias, float* __restrict__ out) {
  __shared__ float patch[64 * 30];
  __shared__ float red[128];
  int pb   = blockIdx.x;
  int owt  = pb % 28;
  int rest = pb / 28;
  int oh   = rest % OHH;
  int n    = rest / OHH;
  int ow0  = owt * 8;
  int tid  = threadIdx.x;
  for (int i = tid; i < 1920; i += 128) {
    int wl = i % 10;
    int rr = (i / 10) % 3;
    int ci = i / 30;
    int wg = ow0 + wl;
    float v = 0.f;
    if (wg < WW) v = x[((size_t)(n * 64 + ci) * HH + (oh + rr)) * WW + wg];
    patch[i] = v;
  }
  __syncthreads();
  int co = tid;
  float a[8];
#pragma unroll
  for (int p = 0; p < 8; ++p) a[p] = bias[co];
  for (int ci = 0; ci < 64; ++ci) {
#pragma unroll
    for (int rr = 0; rr < 3; ++rr)
#pragma unroll
      for (int kw = 0; kw < 3; ++kw) {
        float wvv = wt[(size_t)co * 576 + ci * 9 + rr * 3 + kw];
        const float* pp = &patch[ci * 30 + rr * 10 + kw];
#pragma unroll
        for (int p = 0; p < 8; ++p) a[p] += pp[p] * wvv;
      }
  }
  for (int p = 0; p < 8; ++p) {
    red[tid] = a[p];
    __syncthreads();
    for (int st = 64; st > 0; st >>= 1) {
      if (tid < st) red[tid] = fminf(red[tid], red[tid + st]);
      __syncthreads();
    }
    if (tid == 0 && (ow0 + p) < OWW)
      out[(size_t)n * (OHH * OWW) + (size_t)oh * OWW + ow0 + p] = tanhf(tanhf(red[0]));
    __syncthreads();
  }
}

// ---------------------------------------------------------------------------
extern "C" void kernel_launch(void* const* d_in, const int* in_sizes, int n_in,
                              void* d_out, int out_size, void* d_ws, size_t ws_size,
                              hipStream_t stream) {
  const float* x    = (const float*)d_in[0];
  const float* wt   = (const float*)d_in[1];
  const float* bias = (const float*)d_in[2];
  float* out        = (float*)d_out;

  if (ws_size >= WS_NEED) {
    unsigned char* ws = (unsigned char*)d_ws;
    prep_w_kernel<<<36, 256, 0, stream>>>(wt, ws);
    conv_min_kernel<<<NN * 56 * 4, 256, 0, stream>>>(x, bias, ws, out);
  } else {
    fallback_kernel<<<NN * OHH * 28, 128, 0, stream>>>(x, wt, bias, out);
  }
}